// Round 1
// baseline (1911.777 us; speedup 1.0000x reference)
//
#include <hip/hip_runtime.h>
#include <hip/hip_bf16.h>

#define NPTS   8192
#define NBATCH 8
#define S      1024
#define K      16
#define D      64
#define CIN    67
#define WN     16
#define OUTC   128

// d_out layout (floats): [0,24576) new_xyz [B,3,S]; [24576, 24576+1048576) out [B,128,S];
// [1073152, 1081344) fps_idx as float [B,S]
#define OUT_MAIN 24576
#define OUT_FPS  1073152

// ---------------------------------------------------------------- FPS
__global__ __launch_bounds__(1024)
void fps_kernel(const float* __restrict__ xyz, float* __restrict__ newxyz,
                float* __restrict__ out)
{
#pragma clang fp contract(off)
  const int b   = blockIdx.x;
  const int tid = threadIdx.x;
  const float* xb = xyz + (size_t)b * 3 * NPTS;

  float px[8], py[8], pz[8], dist[8];
#pragma unroll
  for (int i = 0; i < 8; i++) {
    int n = i * 1024 + tid;
    px[i] = xb[n];
    py[i] = xb[NPTS + n];
    pz[i] = xb[2 * NPTS + n];
    dist[i] = 1e10f;
  }

  __shared__ unsigned long long s_best[2];
  __shared__ float s_c[3];
  if (tid == 0) { s_best[0] = 0ull; s_best[1] = 0ull; }
  __syncthreads();

  int far = 0;
  float cx = xb[0], cy = xb[NPTS], cz = xb[2 * NPTS];

  for (int t = 0; t < 1024; t++) {
    const int p = t & 1;
    if (tid == 0) {
      s_best[p ^ 1] = 0ull;                       // re-arm other parity buffer
      out[OUT_FPS + b * 1024 + t] = (float)far;   // fps_idx as float
      out[(b * 3 + 0) * 1024 + t] = cx;           // new_xyz [B,3,S]
      out[(b * 3 + 1) * 1024 + t] = cy;
      out[(b * 3 + 2) * 1024 + t] = cz;
      newxyz[(b * 1024 + t) * 3 + 0] = cx;        // ws copy [B,S,3]
      newxyz[(b * 1024 + t) * 3 + 1] = cy;
      newxyz[(b * 1024 + t) * 3 + 2] = cz;
    }

    // exact update: d = (dx*dx + dy*dy) + dz*dz ; dist = min(dist, d)
    float bd = -1.0f; int bi = 0;
#pragma unroll
    for (int i = 0; i < 8; i++) {
      float dx = px[i] - cx, dy = py[i] - cy, dz = pz[i] - cz;
      float d  = (dx * dx + dy * dy) + dz * dz;
      float nd = fminf(dist[i], d);
      dist[i] = nd;
      if (nd > bd) { bd = nd; bi = i * 1024 + tid; }   // i ascending => lowest idx on tie
    }

    // pack (dist_bits, ~idx): u64 max == (max dist, then min idx)
    unsigned long long key =
        ((unsigned long long)__float_as_uint(bd) << 32) | (unsigned)(~(unsigned)bi);
#pragma unroll
    for (int off = 1; off < 64; off <<= 1) {
      unsigned long long ok = __shfl_xor(key, off);
      if (ok > key) key = ok;
    }
    if ((tid & 63) == 0) atomicMax(&s_best[p], key);
    __syncthreads();

    unsigned long long wk = s_best[p];
    int gi = (int)(~(unsigned)(wk & 0xFFFFFFFFull));

    // owner thread publishes centroid coords
    if (tid == (gi & 1023)) {
      int ii = gi >> 10;
      float ccx = px[0], ccy = py[0], ccz = pz[0];
#pragma unroll
      for (int i = 1; i < 8; i++)
        if (ii == i) { ccx = px[i]; ccy = py[i]; ccz = pz[i]; }
      s_c[0] = ccx; s_c[1] = ccy; s_c[2] = ccz;
    }
    __syncthreads();
    far = gi; cx = s_c[0]; cy = s_c[1]; cz = s_c[2];
  }
}

// ---------------------------------------------------------------- KNN (top-16)
// 8 threads per centroid, each scans a strided 1/8 of the points keeping a sorted
// top-16 (strict < => stable, matches lax.top_k), then an 8-way tournament merge.
__global__ __launch_bounds__(256)
void knn_kernel(const float* __restrict__ xyz, const float* __restrict__ newxyz,
                int* __restrict__ knn)
{
#pragma clang fp contract(off)
  __shared__ float s_cd[32][137];
  __shared__ int   s_ci[32][137];
  const int tid   = threadIdx.x;
  const int cl    = tid >> 3;
  const int chunk = tid & 7;
  const int csel  = blockIdx.x * 32 + cl;
  const int b     = csel >> 10;
  const float* xb = xyz + (size_t)b * 3 * NPTS;
  const float cx = newxyz[csel * 3 + 0];
  const float cy = newxyz[csel * 3 + 1];
  const float cz = newxyz[csel * 3 + 2];

  float nd[16]; int ni[16];
#pragma unroll
  for (int k = 0; k < 16; k++) { nd[k] = 3.4e38f; ni[k] = 0x7FFFFFFF; }

  for (int jj = 0; jj < 1024; jj++) {
    int j = jj * 8 + chunk;
    float dx = xb[j] - cx, dy = xb[NPTS + j] - cy, dz = xb[2 * NPTS + j] - cz;
    float d  = (dx * dx + dy * dy) + dz * dz;
    float cv = d; int iv = j;
#pragma unroll
    for (int k = 0; k < 16; k++) {       // branchless sorted insertion (strict <)
      bool sw = cv < nd[k];
      float tv = nd[k]; int ti = ni[k];
      nd[k] = sw ? cv : tv;  ni[k] = sw ? iv : ti;
      cv    = sw ? tv : cv;  iv    = sw ? ti : iv;
    }
  }
#pragma unroll
  for (int k = 0; k < 16; k++) {
    s_cd[cl][chunk * 17 + k] = nd[k];
    s_ci[cl][chunk * 17 + k] = ni[k];
  }
  s_cd[cl][chunk * 17 + 16] = 3.4e38f;   // sentinel
  s_ci[cl][chunk * 17 + 16] = 0x7FFFFFFF;
  __syncthreads();

  if (tid < 32) {                        // merge: 16 rounds of 8-way tournament
    int pos[8] = {0, 0, 0, 0, 0, 0, 0, 0};
    for (int r = 0; r < 16; r++) {
      float bdv = 3.4e38f; int biv = 0x7FFFFFFF; int bc = 0;
#pragma unroll
      for (int c = 0; c < 8; c++) {
        float dv = s_cd[tid][c * 17 + pos[c]];
        int   iv = s_ci[tid][c * 17 + pos[c]];
        if (dv < bdv || (dv == bdv && iv < biv)) { bdv = dv; biv = iv; bc = c; }
      }
#pragma unroll
      for (int c = 0; c < 8; c++) pos[c] += (c == bc);
      knn[(size_t)(blockIdx.x * 32 + tid) * 16 + r] = biv;
    }
  }
}

// ---------------------------------------------------------------- points transpose [B,64,N] -> [B,N,64]
__global__ __launch_bounds__(256)
void transpose_kernel(const float* __restrict__ pts, float* __restrict__ ptt)
{
  __shared__ float tile[64 * 65];
  const int b  = blockIdx.x >> 7;
  const int n0 = (blockIdx.x & 127) * 64;
  const float* pb = pts + (size_t)b * D * NPTS;
#pragma unroll
  for (int i = 0; i < 16; i++) {
    int s = threadIdx.x + i * 256;
    int nl = s & 63, d = s >> 6;
    tile[d * 65 + nl] = pb[(size_t)d * NPTS + n0 + nl];
  }
  __syncthreads();
  float* ob = ptt + ((size_t)b * NPTS + n0) * D;
#pragma unroll
  for (int i = 0; i < 16; i++) {
    int s = threadIdx.x + i * 256;
    int dl = s & 63, nl = s >> 6;
    ob[(size_t)nl * D + dl] = tile[dl * 65 + nl];
  }
}

// ---------------------------------------------------------------- gather + WeightNet + agg
// one wave per centroid (4 waves/block). agg[csel][c*16+w] = sum_k feat[k][c]*wts[k][w]
__global__ __launch_bounds__(256)
void feat_agg_kernel(const float* __restrict__ xyz, const float* __restrict__ newxyz,
                     const float* __restrict__ ptt, const int* __restrict__ knn,
                     const float* __restrict__ w1, const float* __restrict__ b1,
                     const float* __restrict__ w2, const float* __restrict__ b2,
                     const float* __restrict__ w3, const float* __restrict__ b3,
                     float* __restrict__ agg)
{
  const int wv   = threadIdx.x >> 6;
  const int lane = threadIdx.x & 63;
  const int csel = blockIdx.x * 4 + wv;
  const int b    = csel >> 10;

  __shared__ float s_wts[4][16 * 17];
  __shared__ float s_off[4][16 * 3];
  __shared__ int   s_nk[4][16];

  if (lane < 16) {
    int nk = knn[(size_t)csel * 16 + lane];
    s_nk[wv][lane] = nk;
    const float* xb = xyz + (size_t)b * 3 * NPTS;
    float ox = xb[nk]            - newxyz[csel * 3 + 0];
    float oy = xb[NPTS + nk]     - newxyz[csel * 3 + 1];
    float oz = xb[2 * NPTS + nk] - newxyz[csel * 3 + 2];
    s_off[wv][lane * 3 + 0] = ox;
    s_off[wv][lane * 3 + 1] = oy;
    s_off[wv][lane * 3 + 2] = oz;
    float h1[8], h2[8];
#pragma unroll
    for (int j = 0; j < 8; j++)
      h1[j] = fmaxf(0.f, ox * w1[j] + oy * w1[8 + j] + oz * w1[16 + j] + b1[j]);
#pragma unroll
    for (int j = 0; j < 8; j++) {
      float a = b2[j];
#pragma unroll
      for (int i = 0; i < 8; i++) a = fmaf(h1[i], w2[i * 8 + j], a);
      h2[j] = fmaxf(0.f, a);
    }
#pragma unroll
    for (int w = 0; w < 16; w++) {
      float a = b3[w];
#pragma unroll
      for (int i = 0; i < 8; i++) a = fmaf(h2[i], w3[i * 16 + w], a);
      s_wts[wv][lane * 17 + w] = fmaxf(0.f, a);
    }
  }
  __syncthreads();

  // gather point-feature channel d = lane for all 16 neighbors
  float f[16];
#pragma unroll
  for (int k = 0; k < 16; k++) {
    int nk = s_nk[wv][k];
    f[k] = ptt[((size_t)b * NPTS + nk) * D + lane];
  }

  float acc[16];
#pragma unroll
  for (int w = 0; w < 16; w++) acc[w] = 0.f;
#pragma unroll
  for (int k = 0; k < 16; k++) {
#pragma unroll
    for (int w = 0; w < 16; w++)
      acc[w] = fmaf(f[k], s_wts[wv][k * 17 + w], acc[w]);
  }
  float* arow = agg + (size_t)csel * (CIN * WN) + (3 + lane) * 16;
#pragma unroll
  for (int q = 0; q < 4; q++) {
    float4 v = make_float4(acc[4 * q], acc[4 * q + 1], acc[4 * q + 2], acc[4 * q + 3]);
    *(float4*)(arow + 4 * q) = v;
  }

  if (lane < 48) {                      // xyz-offset channels c = 0..2
    int c = lane >> 4, w = lane & 15;
    float a = 0.f;
#pragma unroll
    for (int k = 0; k < 16; k++)
      a = fmaf(s_off[wv][k * 3 + c], s_wts[wv][k * 17 + w], a);
    agg[(size_t)csel * (CIN * WN) + c * 16 + w] = a;
  }
}

// ---------------------------------------------------------------- GEMM [8192,1072]x[1072,128] + bias + leaky, transposed store
__global__ __launch_bounds__(256)
void gemm_out_kernel(const float* __restrict__ agg, const float* __restrict__ lin_w,
                     const float* __restrict__ lin_b, float* __restrict__ out)
{
  __shared__ float a_t[16 * 68];   // [k][r], stride 68
  __shared__ float b_t[16 * 64];   // [k][c]
  const int tid  = threadIdx.x;
  const int rt   = blockIdx.x >> 1;
  const int ct   = blockIdx.x & 1;
  const int row0 = rt * 64;
  const int c0   = ct * 64;
  const int cg   = tid & 31;   // 2 cols
  const int rg   = tid >> 5;   // 8 rows

  float acc[8][2] = {};
  for (int kt = 0; kt < 67; kt++) {
    const int k0 = kt * 16;
#pragma unroll
    for (int i = 0; i < 4; i++) {
      int s = tid + i * 256;
      int kk = s & 15, r = s >> 4;
      a_t[kk * 68 + r] = agg[(size_t)(row0 + r) * (CIN * WN) + k0 + kk];
    }
#pragma unroll
    for (int i = 0; i < 4; i++) {
      int s = tid + i * 256;
      int c = s & 63, kk = s >> 6;
      b_t[kk * 64 + c] = lin_w[(size_t)(k0 + kk) * OUTC + c0 + c];
    }
    __syncthreads();
#pragma unroll
    for (int kk = 0; kk < 16; kk++) {
      const float4 a0 = *(const float4*)&a_t[kk * 68 + rg * 8];
      const float4 a1 = *(const float4*)&a_t[kk * 68 + rg * 8 + 4];
      float bv0 = b_t[kk * 64 + cg * 2];
      float bv1 = b_t[kk * 64 + cg * 2 + 1];
      float av[8] = {a0.x, a0.y, a0.z, a0.w, a1.x, a1.y, a1.z, a1.w};
#pragma unroll
      for (int rr = 0; rr < 8; rr++) {
        acc[rr][0] = fmaf(av[rr], bv0, acc[rr][0]);
        acc[rr][1] = fmaf(av[rr], bv1, acc[rr][1]);
      }
    }
    __syncthreads();
  }
#pragma unroll
  for (int rr = 0; rr < 8; rr++) {
#pragma unroll
    for (int cc = 0; cc < 2; cc++) {
      int R = row0 + rg * 8 + rr;
      int C = c0 + cg * 2 + cc;
      float v = acc[rr][cc] + lin_b[C];
      v = v > 0.f ? v : 0.1f * v;
      int bb = R >> 10, ss = R & 1023;
      out[OUT_MAIN + ((size_t)(bb * OUTC + C)) * 1024 + ss] = v;
    }
  }
}

// ---------------------------------------------------------------- launch
extern "C" void kernel_launch(void* const* d_in, const int* in_sizes, int n_in,
                              void* d_out, int out_size, void* d_ws, size_t ws_size,
                              hipStream_t stream) {
  const float* xyz    = (const float*)d_in[0];
  const float* points = (const float*)d_in[1];
  const float* w1     = (const float*)d_in[2];
  const float* b1     = (const float*)d_in[3];
  const float* w2     = (const float*)d_in[4];
  const float* b2     = (const float*)d_in[5];
  const float* w3     = (const float*)d_in[6];
  const float* b3     = (const float*)d_in[7];
  const float* lin_w  = (const float*)d_in[8];
  const float* lin_b  = (const float*)d_in[9];
  float* out = (float*)d_out;
  char*  ws  = (char*)d_ws;

  float* newxyz = (float*)(ws);                 // [8,1024,3]      98304 B
  int*   knn    = (int*)  (ws + 98304);         // [8192,16]       524288 B
  float* ptt    = (float*)(ws + 1048576);       // [8,8192,64]     16 MiB
  float* agg    = (float*)(ws + 17825792);      // [8192,1072]     ~33.5 MiB

  fps_kernel<<<NBATCH, 1024, 0, stream>>>(xyz, newxyz, out);
  transpose_kernel<<<NBATCH * 128, 256, 0, stream>>>(points, ptt);
  knn_kernel<<<256, 256, 0, stream>>>(xyz, newxyz, knn);
  feat_agg_kernel<<<2048, 256, 0, stream>>>(xyz, newxyz, ptt, knn,
                                            w1, b1, w2, b2, w3, b3, agg);
  gemm_out_kernel<<<256, 256, 0, stream>>>(agg, lin_w, lin_b, out);
}

// Round 2
// 1664.704 us; speedup vs baseline: 1.1484x; 1.1484x over previous
//
#include <hip/hip_runtime.h>
#include <hip/hip_bf16.h>

#define NPTS   8192
#define NBATCH 8
#define S      1024
#define K      16
#define D      64
#define CIN    67
#define WN     16
#define OUTC   128

// d_out layout (floats): [0,24576) new_xyz [B,3,S]; [24576, 24576+1048576) out [B,128,S];
// [1073152, 1081344) fps_idx as float [B,S]
#define OUT_MAIN 24576
#define OUT_FPS  1073152

// ---------------------------------------------------------------- stage0: FPS (blocks 0..7) + points transpose (blocks 8..1031)
// FPS: 512 threads, 16 pts/thread in registers. Per iter: branchless update+argmax,
// wave shuffle-reduce of packed (dist_bits<<32)|~idx, plain LDS slot per wave
// (double-buffered by parity -> no atomics, ONE barrier/iter), all threads
// redundantly reduce the 8 slots, centroid coords re-fetched by scalar load.
__global__ __launch_bounds__(512)
void stage0_kernel(const float* __restrict__ xyz, const float* __restrict__ pts,
                   float* __restrict__ newxyz, float* __restrict__ ptt,
                   float* __restrict__ out)
{
#pragma clang fp contract(off)
  if (blockIdx.x >= 8) {               // ------- transpose [B,64,N] -> [B,N,64]
    __shared__ float tile[64 * 65];
    const int bid = blockIdx.x - 8;
    const int b   = bid >> 7;
    const int n0  = (bid & 127) * 64;
    const float* pb = pts + (size_t)b * D * NPTS;
#pragma unroll
    for (int i = 0; i < 8; i++) {
      int s = threadIdx.x + i * 512;
      int nl = s & 63, d = s >> 6;
      tile[d * 65 + nl] = pb[(size_t)d * NPTS + n0 + nl];
    }
    __syncthreads();
    float* ob = ptt + ((size_t)b * NPTS + n0) * D;
#pragma unroll
    for (int i = 0; i < 8; i++) {
      int s = threadIdx.x + i * 512;
      int dl = s & 63, nl = s >> 6;
      ob[(size_t)nl * D + dl] = tile[dl * 65 + nl];
    }
    return;
  }

  // ------- FPS
  const int b    = blockIdx.x;
  const int tid  = threadIdx.x;
  const int wave = tid >> 6;
  const int lane = tid & 63;
  const float* xb = xyz + (size_t)b * 3 * NPTS;

  float px[16], py[16], pz[16], dist[16];
#pragma unroll
  for (int i = 0; i < 16; i++) {
    int n = i * 512 + tid;
    px[i] = xb[n];
    py[i] = xb[NPTS + n];
    pz[i] = xb[2 * NPTS + n];
    dist[i] = 1e10f;
  }

  __shared__ unsigned long long slots[2][8];

  int far = 0;
  float cx = xb[0], cy = xb[NPTS], cz = xb[2 * NPTS];

  for (int t = 0; t < 1024; t++) {
    if (tid == 0) {                                  // prev iter's result (fire-and-forget,
      out[OUT_FPS + b * 1024 + t] = (float)far;      // drains well before the barrier)
      out[b * 3072 + t]        = cx;                 // new_xyz [B,3,S]
      out[b * 3072 + 1024 + t] = cy;
      out[b * 3072 + 2048 + t] = cz;
      newxyz[(b * 1024 + t) * 3 + 0] = cx;           // ws copy [B,S,3]
      newxyz[(b * 1024 + t) * 3 + 1] = cy;
      newxyz[(b * 1024 + t) * 3 + 2] = cz;
    }

    // exact update: d = (dx*dx + dy*dy) + dz*dz ; dist = min(dist, d)
    float bd = -1.0f; int bi = 0;
#pragma unroll
    for (int i = 0; i < 16; i++) {
      float dx = px[i] - cx, dy = py[i] - cy, dz = pz[i] - cz;
      float d  = (dx * dx + dy * dy) + dz * dz;
      float nd = fminf(dist[i], d);
      dist[i] = nd;
      if (nd > bd) { bd = nd; bi = i * 512 + tid; }  // i ascending => lowest idx on tie
    }

    // pack (dist_bits, ~idx): u64 max == (max dist, then min idx)
    unsigned long long key =
        ((unsigned long long)__float_as_uint(bd) << 32) | (unsigned)(~(unsigned)bi);
#pragma unroll
    for (int off = 1; off < 64; off <<= 1) {
      unsigned long long ok = __shfl_xor(key, off);
      key = ok > key ? ok : key;
    }
    if (lane == 0) slots[t & 1][wave] = key;
    __syncthreads();                                  // the ONLY barrier per iter

    unsigned long long wk = slots[t & 1][0];
#pragma unroll
    for (int w = 1; w < 8; w++) {
      unsigned long long o = slots[t & 1][w];
      wk = o > wk ? o : wk;
    }
    int gi = (int)(~(unsigned)(wk & 0xFFFFFFFFull));
    int gs = __builtin_amdgcn_readfirstlane(gi);      // scalar load path (L2-resident)
    far = gs;
    cx = xb[gs]; cy = xb[NPTS + gs]; cz = xb[2 * NPTS + gs];
  }
}

// ---------------------------------------------------------------- KNN (top-16)
// 16 threads per centroid (512 pts each, strided) -> 2 waves/SIMD occupancy.
// Sorted top-16 insertion per chunk (strict < => stable), then a 16-way
// tournament merge on u64-packed (dist_bits<<32)|idx keys (lex == (d, idx)).
__global__ __launch_bounds__(256)
void knn_kernel(const float* __restrict__ xyz, const float* __restrict__ newxyz,
                int* __restrict__ knn)
{
#pragma clang fp contract(off)
  __shared__ unsigned long long s_k[16][16 * 17];   // [cent][chunk*17 + k], 34 KB
  const int tid   = threadIdx.x;
  const int cl    = tid >> 4;
  const int chunk = tid & 15;
  const int csel  = blockIdx.x * 16 + cl;
  const int b     = csel >> 10;                     // block-uniform (64 blocks/batch)
  const float* xb = xyz + (size_t)b * 3 * NPTS;
  const float cx = newxyz[csel * 3 + 0];
  const float cy = newxyz[csel * 3 + 1];
  const float cz = newxyz[csel * 3 + 2];

  float nd[16]; int ni[16];
#pragma unroll
  for (int k = 0; k < 16; k++) { nd[k] = 3.4e38f; ni[k] = 0x7FFFFFFF; }

  for (int jj = 0; jj < 512; jj++) {
    int j = jj * 16 + chunk;
    float dx = xb[j] - cx, dy = xb[NPTS + j] - cy, dz = xb[2 * NPTS + j] - cz;
    float d  = (dx * dx + dy * dy) + dz * dz;
    float cv = d; int iv = j;
#pragma unroll
    for (int k = 0; k < 16; k++) {       // branchless sorted insertion (strict <)
      bool sw = cv < nd[k];
      float tv = nd[k]; int ti = ni[k];
      nd[k] = sw ? cv : tv;  ni[k] = sw ? iv : ti;
      cv    = sw ? tv : cv;  iv    = sw ? ti : iv;
    }
  }
#pragma unroll
  for (int k = 0; k < 16; k++)
    s_k[cl][chunk * 17 + k] =
        ((unsigned long long)__float_as_uint(nd[k]) << 32) | (unsigned)ni[k];
  s_k[cl][chunk * 17 + 16] = ~0ull;      // sentinel
  __syncthreads();

  if (tid < 16) {                        // merge: 16 rounds of 16-way tournament (u64 min)
    int pos[16];
#pragma unroll
    for (int c = 0; c < 16; c++) pos[c] = 0;
    for (int r = 0; r < 16; r++) {
      unsigned long long bk = ~0ull; int bc = 0;
#pragma unroll
      for (int c = 0; c < 16; c++) {
        unsigned long long kv = s_k[tid][c * 17 + pos[c]];
        if (kv < bk) { bk = kv; bc = c; }
      }
#pragma unroll
      for (int c = 0; c < 16; c++) pos[c] += (c == bc);
      knn[(size_t)(blockIdx.x * 16 + tid) * 16 + r] = (int)(bk & 0xFFFFFFFFull);
    }
  }
}

// ---------------------------------------------------------------- gather + WeightNet + agg
// one wave per centroid (4 waves/block). agg[csel][c*16+w] = sum_k feat[k][c]*wts[k][w]
__global__ __launch_bounds__(256)
void feat_agg_kernel(const float* __restrict__ xyz, const float* __restrict__ newxyz,
                     const float* __restrict__ ptt, const int* __restrict__ knn,
                     const float* __restrict__ w1, const float* __restrict__ b1,
                     const float* __restrict__ w2, const float* __restrict__ b2,
                     const float* __restrict__ w3, const float* __restrict__ b3,
                     float* __restrict__ agg)
{
  const int wv   = threadIdx.x >> 6;
  const int lane = threadIdx.x & 63;
  const int csel = blockIdx.x * 4 + wv;
  const int b    = csel >> 10;

  __shared__ float s_wts[4][16 * 17];
  __shared__ float s_off[4][16 * 3];
  __shared__ int   s_nk[4][16];

  if (lane < 16) {
    int nk = knn[(size_t)csel * 16 + lane];
    s_nk[wv][lane] = nk;
    const float* xb = xyz + (size_t)b * 3 * NPTS;
    float ox = xb[nk]            - newxyz[csel * 3 + 0];
    float oy = xb[NPTS + nk]     - newxyz[csel * 3 + 1];
    float oz = xb[2 * NPTS + nk] - newxyz[csel * 3 + 2];
    s_off[wv][lane * 3 + 0] = ox;
    s_off[wv][lane * 3 + 1] = oy;
    s_off[wv][lane * 3 + 2] = oz;
    float h1[8], h2[8];
#pragma unroll
    for (int j = 0; j < 8; j++)
      h1[j] = fmaxf(0.f, ox * w1[j] + oy * w1[8 + j] + oz * w1[16 + j] + b1[j]);
#pragma unroll
    for (int j = 0; j < 8; j++) {
      float a = b2[j];
#pragma unroll
      for (int i = 0; i < 8; i++) a = fmaf(h1[i], w2[i * 8 + j], a);
      h2[j] = fmaxf(0.f, a);
    }
#pragma unroll
    for (int w = 0; w < 16; w++) {
      float a = b3[w];
#pragma unroll
      for (int i = 0; i < 8; i++) a = fmaf(h2[i], w3[i * 16 + w], a);
      s_wts[wv][lane * 17 + w] = fmaxf(0.f, a);
    }
  }
  __syncthreads();

  // gather point-feature channel d = lane for all 16 neighbors
  float f[16];
#pragma unroll
  for (int k = 0; k < 16; k++) {
    int nk = s_nk[wv][k];
    f[k] = ptt[((size_t)b * NPTS + nk) * D + lane];
  }

  float acc[16];
#pragma unroll
  for (int w = 0; w < 16; w++) acc[w] = 0.f;
#pragma unroll
  for (int k = 0; k < 16; k++) {
#pragma unroll
    for (int w = 0; w < 16; w++)
      acc[w] = fmaf(f[k], s_wts[wv][k * 17 + w], acc[w]);
  }
  float* arow = agg + (size_t)csel * (CIN * WN) + (3 + lane) * 16;
#pragma unroll
  for (int q = 0; q < 4; q++) {
    float4 v = make_float4(acc[4 * q], acc[4 * q + 1], acc[4 * q + 2], acc[4 * q + 3]);
    *(float4*)(arow + 4 * q) = v;
  }

  if (lane < 48) {                      // xyz-offset channels c = 0..2
    int c = lane >> 4, w = lane & 15;
    float a = 0.f;
#pragma unroll
    for (int k = 0; k < 16; k++)
      a = fmaf(s_off[wv][k * 3 + c], s_wts[wv][k * 17 + w], a);
    agg[(size_t)csel * (CIN * WN) + c * 16 + w] = a;
  }
}

// ---------------------------------------------------------------- GEMM [8192,1072]x[1072,128] + bias + leaky, transposed store
__global__ __launch_bounds__(256)
void gemm_out_kernel(const float* __restrict__ agg, const float* __restrict__ lin_w,
                     const float* __restrict__ lin_b, float* __restrict__ out)
{
  __shared__ float a_t[16 * 68];   // [k][r], stride 68
  __shared__ float b_t[16 * 64];   // [k][c]
  const int tid  = threadIdx.x;
  const int rt   = blockIdx.x >> 1;
  const int ct   = blockIdx.x & 1;
  const int row0 = rt * 64;
  const int c0   = ct * 64;
  const int cg   = tid & 31;   // 2 cols
  const int rg   = tid >> 5;   // 8 rows

  float acc[8][2] = {};
  for (int kt = 0; kt < 67; kt++) {
    const int k0 = kt * 16;
#pragma unroll
    for (int i = 0; i < 4; i++) {
      int s = tid + i * 256;
      int kk = s & 15, r = s >> 4;
      a_t[kk * 68 + r] = agg[(size_t)(row0 + r) * (CIN * WN) + k0 + kk];
    }
#pragma unroll
    for (int i = 0; i < 4; i++) {
      int s = tid + i * 256;
      int c = s & 63, kk = s >> 6;
      b_t[kk * 64 + c] = lin_w[(size_t)(k0 + kk) * OUTC + c0 + c];
    }
    __syncthreads();
#pragma unroll
    for (int kk = 0; kk < 16; kk++) {
      const float4 a0 = *(const float4*)&a_t[kk * 68 + rg * 8];
      const float4 a1 = *(const float4*)&a_t[kk * 68 + rg * 8 + 4];
      float bv0 = b_t[kk * 64 + cg * 2];
      float bv1 = b_t[kk * 64 + cg * 2 + 1];
      float av[8] = {a0.x, a0.y, a0.z, a0.w, a1.x, a1.y, a1.z, a1.w};
#pragma unroll
      for (int rr = 0; rr < 8; rr++) {
        acc[rr][0] = fmaf(av[rr], bv0, acc[rr][0]);
        acc[rr][1] = fmaf(av[rr], bv1, acc[rr][1]);
      }
    }
    __syncthreads();
  }
#pragma unroll
  for (int rr = 0; rr < 8; rr++) {
#pragma unroll
    for (int cc = 0; cc < 2; cc++) {
      int R = row0 + rg * 8 + rr;
      int C = c0 + cg * 2 + cc;
      float v = acc[rr][cc] + lin_b[C];
      v = v > 0.f ? v : 0.1f * v;
      int bb = R >> 10, ss = R & 1023;
      out[OUT_MAIN + ((size_t)(bb * OUTC + C)) * 1024 + ss] = v;
    }
  }
}

// ---------------------------------------------------------------- launch
extern "C" void kernel_launch(void* const* d_in, const int* in_sizes, int n_in,
                              void* d_out, int out_size, void* d_ws, size_t ws_size,
                              hipStream_t stream) {
  const float* xyz    = (const float*)d_in[0];
  const float* points = (const float*)d_in[1];
  const float* w1     = (const float*)d_in[2];
  const float* b1     = (const float*)d_in[3];
  const float* w2     = (const float*)d_in[4];
  const float* b2     = (const float*)d_in[5];
  const float* w3     = (const float*)d_in[6];
  const float* b3     = (const float*)d_in[7];
  const float* lin_w  = (const float*)d_in[8];
  const float* lin_b  = (const float*)d_in[9];
  float* out = (float*)d_out;
  char*  ws  = (char*)d_ws;

  float* newxyz = (float*)(ws);                 // [8,1024,3]      98304 B
  int*   knn    = (int*)  (ws + 98304);         // [8192,16]       524288 B
  float* ptt    = (float*)(ws + 1048576);       // [8,8192,64]     16 MiB
  float* agg    = (float*)(ws + 17825792);      // [8192,1072]     ~33.5 MiB

  stage0_kernel<<<8 + NBATCH * 128, 512, 0, stream>>>(xyz, points, newxyz, ptt, out);
  knn_kernel<<<512, 256, 0, stream>>>(xyz, newxyz, knn);
  feat_agg_kernel<<<2048, 256, 0, stream>>>(xyz, newxyz, ptt, knn,
                                            w1, b1, w2, b2, w3, b3, agg);
  gemm_out_kernel<<<256, 256, 0, stream>>>(agg, lin_w, lin_b, out);
}

// Round 3
// 1392.972 us; speedup vs baseline: 1.3724x; 1.1951x over previous
//
#include <hip/hip_runtime.h>
#include <hip/hip_bf16.h>

#define NPTS   8192
#define NBATCH 8
#define S      1024
#define K      16
#define D      64
#define CIN    67
#define WN     16
#define OUTC   128

// d_out layout (floats): [0,24576) new_xyz [B,3,S]; [24576, 24576+1048576) out [B,128,S];
// [1073152, 1081344) fps_idx as float [B,S]
#define OUT_MAIN 24576
#define OUT_FPS  1073152

// DPP-based u64 max reduce step (result accumulates toward lane 63).
// bound_ctrl=true / old=0: invalid-source lanes contribute 0 (identity for max,
// since key = (positive-float bits << 32) | ~idx is always > 0 when it matters).
template <int CTRL, int RM>
__device__ __forceinline__ unsigned long long dpp_max_step(unsigned long long key) {
  int lo = __builtin_amdgcn_update_dpp(0, (int)(unsigned)(key & 0xFFFFFFFFull), CTRL, RM, 0xF, true);
  int hi = __builtin_amdgcn_update_dpp(0, (int)(unsigned)(key >> 32),           CTRL, RM, 0xF, true);
  unsigned long long o = ((unsigned long long)(unsigned)hi << 32) | (unsigned)lo;
  return o > key ? o : key;
}

// ---------------------------------------------------------------- stage0: FPS (blocks 0..7) + points transpose (blocks 8..1031)
// FPS: 256 threads, 32 pts/thread in registers; xyz also staged to LDS for the
// centroid re-fetch. Per iter: branchless update+argmax (VALU floor ~770 cy),
// DPP wave-reduce of packed (dist_bits<<32)|~idx (no DS ops), lane-63 slot
// write, ONE barrier, all-thread 4-slot reduce, broadcast ds_read of centroid.
// No global traffic inside the loop: results buffered in LDS hist[1024],
// written coalesced at the end.
__global__ __launch_bounds__(256)
void stage0_kernel(const float* __restrict__ xyz, const float* __restrict__ pts,
                   float* __restrict__ newxyz, float* __restrict__ ptt,
                   float* __restrict__ out)
{
#pragma clang fp contract(off)
  __shared__ float s_x[NPTS], s_y[NPTS], s_z[NPTS];   // 96 KB (also transpose tile)
  __shared__ float4 hist[1024];                        // 16 KB
  __shared__ unsigned long long slots[2][4];

  if (blockIdx.x >= 8) {               // ------- transpose [B,64,N] -> [B,N,64]
    const int bid = blockIdx.x - 8;
    const int b   = bid >> 7;
    const int n0  = (bid & 127) * 64;
    const float* pb = pts + (size_t)b * D * NPTS;
#pragma unroll
    for (int i = 0; i < 16; i++) {
      int s = threadIdx.x + i * 256;
      int nl = s & 63, d = s >> 6;
      s_x[d * 65 + nl] = pb[(size_t)d * NPTS + n0 + nl];   // 64*65=4160 <= 8192 floats
    }
    __syncthreads();
    float* ob = ptt + ((size_t)b * NPTS + n0) * D;
#pragma unroll
    for (int i = 0; i < 16; i++) {
      int s = threadIdx.x + i * 256;
      int dl = s & 63, nl = s >> 6;
      ob[(size_t)nl * D + dl] = s_x[dl * 65 + nl];
    }
    return;
  }

  // ------- FPS
  const int b    = blockIdx.x;
  const int tid  = threadIdx.x;
  const int wave = tid >> 6;
  const int lane = tid & 63;
  const float* xb = xyz + (size_t)b * 3 * NPTS;

  float px[32], py[32], pz[32], dist[32];
#pragma unroll
  for (int i = 0; i < 32; i++) {
    int n = i * 256 + tid;
    px[i] = xb[n];
    py[i] = xb[NPTS + n];
    pz[i] = xb[2 * NPTS + n];
    dist[i] = 1e10f;
    s_x[n] = px[i]; s_y[n] = py[i]; s_z[n] = pz[i];     // LDS copy for coord re-fetch
  }
  // staging writes are ordered before first LDS coord read by iter-0's barrier

  int far = 0;
  float cx = xb[0], cy = xb[NPTS], cz = xb[2 * NPTS];

  for (int t = 0; t < 1024; t++) {
    if (tid == (t & 255))                               // buffer result, no global traffic
      hist[t] = make_float4(cx, cy, cz, (float)far);

    // exact update: d = (dx*dx + dy*dy) + dz*dz ; dist = min(dist, d)
    float bd = -1.0f; int bi = 0;
#pragma unroll
    for (int i = 0; i < 32; i++) {
      float dx = px[i] - cx, dy = py[i] - cy, dz = pz[i] - cz;
      float d  = (dx * dx + dy * dy) + dz * dz;
      float nd = fminf(dist[i], d);
      dist[i] = nd;
      if (nd > bd) { bd = nd; bi = i * 256 + tid; }     // i ascending => lowest idx on tie
    }

    // pack (dist_bits, ~idx): u64 max == (max dist, then min idx)
    unsigned long long key =
        ((unsigned long long)__float_as_uint(bd) << 32) | (unsigned)(~(unsigned)bi);
    key = dpp_max_step<0x111, 0xF>(key);   // row_shr:1
    key = dpp_max_step<0x112, 0xF>(key);   // row_shr:2
    key = dpp_max_step<0x114, 0xF>(key);   // row_shr:4
    key = dpp_max_step<0x118, 0xF>(key);   // row_shr:8
    key = dpp_max_step<0x142, 0xA>(key);   // row_bcast:15 -> rows 1,3
    key = dpp_max_step<0x143, 0xC>(key);   // row_bcast:31 -> rows 2,3
    if (lane == 63) slots[t & 1][wave] = key;           // wave max lives in lane 63
    __syncthreads();                                    // the ONLY barrier per iter

    unsigned long long k0 = slots[t & 1][0], k1 = slots[t & 1][1];
    unsigned long long k2 = slots[t & 1][2], k3 = slots[t & 1][3];
    k0 = k1 > k0 ? k1 : k0;
    k2 = k3 > k2 ? k3 : k2;
    k0 = k2 > k0 ? k2 : k0;
    int gi = (int)(~(unsigned)(k0 & 0xFFFFFFFFull));
    far = gi;
    cx = s_x[gi]; cy = s_y[gi]; cz = s_z[gi];           // broadcast ds_read, ~120 cy
  }
  __syncthreads();

  // coalesced endgame writes
#pragma unroll
  for (int j = 0; j < 4; j++) {
    int t = j * 256 + tid;
    float4 h = hist[t];
    out[OUT_FPS + b * 1024 + t] = h.w;                  // fps_idx as float
    out[b * 3072 + t]           = h.x;                  // new_xyz [B,3,S]
    out[b * 3072 + 1024 + t]    = h.y;
    out[b * 3072 + 2048 + t]    = h.z;
    newxyz[(b * 1024 + t) * 3 + 0] = h.x;               // ws copy [B,S,3]
    newxyz[(b * 1024 + t) * 3 + 1] = h.y;
    newxyz[(b * 1024 + t) * 3 + 2] = h.z;
  }
}

// ---------------------------------------------------------------- KNN (top-16)
// 16 threads per centroid (512 pts each, strided). Sorted top-16 insertion per
// chunk (strict < => stable == ascending idx on ties), then a 16-way
// tournament merge on u64-packed (dist_bits<<32)|idx keys (lex == (d, idx)).
__global__ __launch_bounds__(256)
void knn_kernel(const float* __restrict__ xyz, const float* __restrict__ newxyz,
                int* __restrict__ knn)
{
#pragma clang fp contract(off)
  __shared__ unsigned long long s_k[16][16 * 17];   // [cent][chunk*17 + k], 34 KB
  const int tid   = threadIdx.x;
  const int cl    = tid >> 4;
  const int chunk = tid & 15;
  const int csel  = blockIdx.x * 16 + cl;
  const int b     = csel >> 10;                     // block-uniform (64 blocks/batch)
  const float* xb = xyz + (size_t)b * 3 * NPTS;
  const float cx = newxyz[csel * 3 + 0];
  const float cy = newxyz[csel * 3 + 1];
  const float cz = newxyz[csel * 3 + 2];

  float nd[16]; int ni[16];
#pragma unroll
  for (int k = 0; k < 16; k++) { nd[k] = 3.4e38f; ni[k] = 0x7FFFFFFF; }

  for (int jj = 0; jj < 512; jj++) {
    int j = jj * 16 + chunk;
    float dx = xb[j] - cx, dy = xb[NPTS + j] - cy, dz = xb[2 * NPTS + j] - cz;
    float d  = (dx * dx + dy * dy) + dz * dz;
    float cv = d; int iv = j;
#pragma unroll
    for (int k = 0; k < 16; k++) {       // branchless sorted insertion (strict <)
      bool sw = cv < nd[k];
      float tv = nd[k]; int ti = ni[k];
      nd[k] = sw ? cv : tv;  ni[k] = sw ? iv : ti;
      cv    = sw ? tv : cv;  iv    = sw ? ti : iv;
    }
  }
#pragma unroll
  for (int k = 0; k < 16; k++)
    s_k[cl][chunk * 17 + k] =
        ((unsigned long long)__float_as_uint(nd[k]) << 32) | (unsigned)ni[k];
  s_k[cl][chunk * 17 + 16] = ~0ull;      // sentinel
  __syncthreads();

  if (tid < 16) {                        // merge: 16 rounds of 16-way tournament (u64 min)
    int pos[16];
#pragma unroll
    for (int c = 0; c < 16; c++) pos[c] = 0;
    for (int r = 0; r < 16; r++) {
      unsigned long long bk = ~0ull; int bc = 0;
#pragma unroll
      for (int c = 0; c < 16; c++) {
        unsigned long long kv = s_k[tid][c * 17 + pos[c]];
        if (kv < bk) { bk = kv; bc = c; }
      }
#pragma unroll
      for (int c = 0; c < 16; c++) pos[c] += (c == bc);
      knn[(size_t)(blockIdx.x * 16 + tid) * 16 + r] = (int)(bk & 0xFFFFFFFFull);
    }
  }
}

// ---------------------------------------------------------------- gather + WeightNet + agg
// one wave per centroid (4 waves/block). agg[csel][c*16+w] = sum_k feat[k][c]*wts[k][w]
__global__ __launch_bounds__(256)
void feat_agg_kernel(const float* __restrict__ xyz, const float* __restrict__ newxyz,
                     const float* __restrict__ ptt, const int* __restrict__ knn,
                     const float* __restrict__ w1, const float* __restrict__ b1,
                     const float* __restrict__ w2, const float* __restrict__ b2,
                     const float* __restrict__ w3, const float* __restrict__ b3,
                     float* __restrict__ agg)
{
  const int wv   = threadIdx.x >> 6;
  const int lane = threadIdx.x & 63;
  const int csel = blockIdx.x * 4 + wv;
  const int b    = csel >> 10;

  __shared__ float s_wts[4][16 * 17];
  __shared__ float s_off[4][16 * 3];
  __shared__ int   s_nk[4][16];

  if (lane < 16) {
    int nk = knn[(size_t)csel * 16 + lane];
    s_nk[wv][lane] = nk;
    const float* xb = xyz + (size_t)b * 3 * NPTS;
    float ox = xb[nk]            - newxyz[csel * 3 + 0];
    float oy = xb[NPTS + nk]     - newxyz[csel * 3 + 1];
    float oz = xb[2 * NPTS + nk] - newxyz[csel * 3 + 2];
    s_off[wv][lane * 3 + 0] = ox;
    s_off[wv][lane * 3 + 1] = oy;
    s_off[wv][lane * 3 + 2] = oz;
    float h1[8], h2[8];
#pragma unroll
    for (int j = 0; j < 8; j++)
      h1[j] = fmaxf(0.f, ox * w1[j] + oy * w1[8 + j] + oz * w1[16 + j] + b1[j]);
#pragma unroll
    for (int j = 0; j < 8; j++) {
      float a = b2[j];
#pragma unroll
      for (int i = 0; i < 8; i++) a = fmaf(h1[i], w2[i * 8 + j], a);
      h2[j] = fmaxf(0.f, a);
    }
#pragma unroll
    for (int w = 0; w < 16; w++) {
      float a = b3[w];
#pragma unroll
      for (int i = 0; i < 8; i++) a = fmaf(h2[i], w3[i * 16 + w], a);
      s_wts[wv][lane * 17 + w] = fmaxf(0.f, a);
    }
  }
  __syncthreads();

  // gather point-feature channel d = lane for all 16 neighbors
  float f[16];
#pragma unroll
  for (int k = 0; k < 16; k++) {
    int nk = s_nk[wv][k];
    f[k] = ptt[((size_t)b * NPTS + nk) * D + lane];
  }

  float acc[16];
#pragma unroll
  for (int w = 0; w < 16; w++) acc[w] = 0.f;
#pragma unroll
  for (int k = 0; k < 16; k++) {
#pragma unroll
    for (int w = 0; w < 16; w++)
      acc[w] = fmaf(f[k], s_wts[wv][k * 17 + w], acc[w]);
  }
  float* arow = agg + (size_t)csel * (CIN * WN) + (3 + lane) * 16;
#pragma unroll
  for (int q = 0; q < 4; q++) {
    float4 v = make_float4(acc[4 * q], acc[4 * q + 1], acc[4 * q + 2], acc[4 * q + 3]);
    *(float4*)(arow + 4 * q) = v;
  }

  if (lane < 48) {                      // xyz-offset channels c = 0..2
    int c = lane >> 4, w = lane & 15;
    float a = 0.f;
#pragma unroll
    for (int k = 0; k < 16; k++)
      a = fmaf(s_off[wv][k * 3 + c], s_wts[wv][k * 17 + w], a);
    agg[(size_t)csel * (CIN * WN) + c * 16 + w] = a;
  }
}

// ---------------------------------------------------------------- GEMM [8192,1072]x[1072,128] + bias + leaky, transposed store
__global__ __launch_bounds__(256)
void gemm_out_kernel(const float* __restrict__ agg, const float* __restrict__ lin_w,
                     const float* __restrict__ lin_b, float* __restrict__ out)
{
  __shared__ float a_t[16 * 68];   // [k][r], stride 68
  __shared__ float b_t[16 * 64];   // [k][c]
  const int tid  = threadIdx.x;
  const int rt   = blockIdx.x >> 1;
  const int ct   = blockIdx.x & 1;
  const int row0 = rt * 64;
  const int c0   = ct * 64;
  const int cg   = tid & 31;   // 2 cols
  const int rg   = tid >> 5;   // 8 rows

  float acc[8][2] = {};
  for (int kt = 0; kt < 67; kt++) {
    const int k0 = kt * 16;
#pragma unroll
    for (int i = 0; i < 4; i++) {
      int s = tid + i * 256;
      int kk = s & 15, r = s >> 4;
      a_t[kk * 68 + r] = agg[(size_t)(row0 + r) * (CIN * WN) + k0 + kk];
    }
#pragma unroll
    for (int i = 0; i < 4; i++) {
      int s = tid + i * 256;
      int c = s & 63, kk = s >> 6;
      b_t[kk * 64 + c] = lin_w[(size_t)(k0 + kk) * OUTC + c0 + c];
    }
    __syncthreads();
#pragma unroll
    for (int kk = 0; kk < 16; kk++) {
      const float4 a0 = *(const float4*)&a_t[kk * 68 + rg * 8];
      const float4 a1 = *(const float4*)&a_t[kk * 68 + rg * 8 + 4];
      float bv0 = b_t[kk * 64 + cg * 2];
      float bv1 = b_t[kk * 64 + cg * 2 + 1];
      float av[8] = {a0.x, a0.y, a0.z, a0.w, a1.x, a1.y, a1.z, a1.w};
#pragma unroll
      for (int rr = 0; rr < 8; rr++) {
        acc[rr][0] = fmaf(av[rr], bv0, acc[rr][0]);
        acc[rr][1] = fmaf(av[rr], bv1, acc[rr][1]);
      }
    }
    __syncthreads();
  }
#pragma unroll
  for (int rr = 0; rr < 8; rr++) {
#pragma unroll
    for (int cc = 0; cc < 2; cc++) {
      int R = row0 + rg * 8 + rr;
      int C = c0 + cg * 2 + cc;
      float v = acc[rr][cc] + lin_b[C];
      v = v > 0.f ? v : 0.1f * v;
      int bb = R >> 10, ss = R & 1023;
      out[OUT_MAIN + ((size_t)(bb * OUTC + C)) * 1024 + ss] = v;
    }
  }
}

// ---------------------------------------------------------------- launch
extern "C" void kernel_launch(void* const* d_in, const int* in_sizes, int n_in,
                              void* d_out, int out_size, void* d_ws, size_t ws_size,
                              hipStream_t stream) {
  const float* xyz    = (const float*)d_in[0];
  const float* points = (const float*)d_in[1];
  const float* w1     = (const float*)d_in[2];
  const float* b1     = (const float*)d_in[3];
  const float* w2     = (const float*)d_in[4];
  const float* b2     = (const float*)d_in[5];
  const float* w3     = (const float*)d_in[6];
  const float* b3     = (const float*)d_in[7];
  const float* lin_w  = (const float*)d_in[8];
  const float* lin_b  = (const float*)d_in[9];
  float* out = (float*)d_out;
  char*  ws  = (char*)d_ws;

  float* newxyz = (float*)(ws);                 // [8,1024,3]      98304 B
  int*   knn    = (int*)  (ws + 98304);         // [8192,16]       524288 B
  float* ptt    = (float*)(ws + 1048576);       // [8,8192,64]     16 MiB
  float* agg    = (float*)(ws + 17825792);      // [8192,1072]     ~33.5 MiB

  stage0_kernel<<<8 + NBATCH * 128, 256, 0, stream>>>(xyz, points, newxyz, ptt, out);
  knn_kernel<<<512, 256, 0, stream>>>(xyz, newxyz, knn);
  feat_agg_kernel<<<2048, 256, 0, stream>>>(xyz, newxyz, ptt, knn,
                                            w1, b1, w2, b2, w3, b3, agg);
  gemm_out_kernel<<<256, 256, 0, stream>>>(agg, lin_w, lin_b, out);
}

// Round 4
// 1364.762 us; speedup vs baseline: 1.4008x; 1.0207x over previous
//
#include <hip/hip_runtime.h>
#include <hip/hip_bf16.h>

#define NPTS   8192
#define NBATCH 8
#define S      1024
#define K      16
#define D      64
#define CIN    67
#define WN     16
#define OUTC   128

// d_out layout (floats): [0,24576) new_xyz [B,3,S]; [24576, 24576+1048576) out [B,128,S];
// [1073152, 1081344) fps_idx as float [B,S]
#define OUT_MAIN 24576
#define OUT_FPS  1073152

typedef float v2f __attribute__((ext_vector_type(2)));

// DPP-based u64 max reduce step (result accumulates toward lane 63).
// bound_ctrl=true / old=0: invalid-source lanes contribute 0 (identity for max,
// since key = (positive-float bits << 32) | ~idx is always > 0 when it matters).
template <int CTRL, int RM>
__device__ __forceinline__ unsigned long long dpp_max_step(unsigned long long key) {
  int lo = __builtin_amdgcn_update_dpp(0, (int)(unsigned)(key & 0xFFFFFFFFull), CTRL, RM, 0xF, true);
  int hi = __builtin_amdgcn_update_dpp(0, (int)(unsigned)(key >> 32),           CTRL, RM, 0xF, true);
  unsigned long long o = ((unsigned long long)(unsigned)hi << 32) | (unsigned)lo;
  return o > key ? o : key;
}

// ---------------------------------------------------------------- stage0: FPS (blocks 0..7) + points transpose (blocks 8..1031)
// FPS: 512 threads, 16 pts/thread as 8 float2 pairs -> v_pk_add/v_pk_mul_f32
// (IEEE-identical to scalar; min + argmax per half stay scalar). Argmax tracks
// the chunk index as an inline-const cndmask; full u64 keys (dist_bits<<32|~idx)
// are formed once per iter so all tie-breaks (lowest idx) stay exact, including
// the even/odd half combine. DPP wave-reduce, lane-63 slot write, ONE barrier,
// 8-slot tree reduce, broadcast ds_read of centroid from LDS-staged xyz.
// No global traffic in the loop: results buffered in LDS hist, written at end.
__global__ __launch_bounds__(512)
void stage0_kernel(const float* __restrict__ xyz, const float* __restrict__ pts,
                   float* __restrict__ newxyz, float* __restrict__ ptt,
                   float* __restrict__ out)
{
#pragma clang fp contract(off)
  __shared__ float s_x[NPTS], s_y[NPTS], s_z[NPTS];   // 96 KB (also transpose tile)
  __shared__ float4 hist[1024];                        // 16 KB
  __shared__ unsigned long long slots[2][8];

  if (blockIdx.x >= 8) {               // ------- transpose [B,64,N] -> [B,N,64]
    const int bid = blockIdx.x - 8;
    const int b   = bid >> 7;
    const int n0  = (bid & 127) * 64;
    const float* pb = pts + (size_t)b * D * NPTS;
#pragma unroll
    for (int i = 0; i < 8; i++) {
      int s = threadIdx.x + i * 512;
      int nl = s & 63, d = s >> 6;
      s_x[d * 65 + nl] = pb[(size_t)d * NPTS + n0 + nl];   // 64*65=4160 <= 8192 floats
    }
    __syncthreads();
    float* ob = ptt + ((size_t)b * NPTS + n0) * D;
#pragma unroll
    for (int i = 0; i < 8; i++) {
      int s = threadIdx.x + i * 512;
      int dl = s & 63, nl = s >> 6;
      ob[(size_t)nl * D + dl] = s_x[dl * 65 + nl];
    }
    return;
  }

  // ------- FPS
  const int b    = blockIdx.x;
  const int tid  = threadIdx.x;
  const int wave = tid >> 6;
  const int lane = tid & 63;
  const float* xb = xyz + (size_t)b * 3 * NPTS;

  v2f px[8], py[8], pz[8], dist[8];
#pragma unroll
  for (int p = 0; p < 8; p++) {
    int ne = (2 * p) * 512 + tid;
    int no = ne + 512;
    px[p] = (v2f){xb[ne], xb[no]};
    py[p] = (v2f){xb[NPTS + ne], xb[NPTS + no]};
    pz[p] = (v2f){xb[2 * NPTS + ne], xb[2 * NPTS + no]};
    dist[p] = (v2f){1e10f, 1e10f};
    s_x[ne] = px[p].x; s_x[no] = px[p].y;               // LDS copy for coord re-fetch
    s_y[ne] = py[p].x; s_y[no] = py[p].y;
    s_z[ne] = pz[p].x; s_z[no] = pz[p].y;
  }
  // staging writes are ordered before first LDS coord read by iter-0's barrier

  int far = 0;
  float cx = xb[0], cy = xb[NPTS], cz = xb[2 * NPTS];

  for (int t = 0; t < 1024; t++) {
    if (tid == (t & 511))                               // buffer result, no global traffic
      hist[t] = make_float4(cx, cy, cz, (float)far);

    const v2f c2x = (v2f){cx, cx}, c2y = (v2f){cy, cy}, c2z = (v2f){cz, cz};

    // exact per-half update: d = (dx*dx + dy*dy) + dz*dz ; dist = min(dist, d)
    float bd_e = -1.0f, bd_o = -1.0f;
    int   ce   = 0,     co   = 0;       // winning chunk index per half (inline consts)
#pragma unroll
    for (int p = 0; p < 8; p++) {
      v2f dx = px[p] - c2x, dy = py[p] - c2y, dz = pz[p] - c2z;
      v2f d  = (dx * dx + dy * dy) + dz * dz;
      float nde = fminf(dist[p].x, d.x);
      float ndo = fminf(dist[p].y, d.y);
      dist[p].x = nde;
      dist[p].y = ndo;
      if (nde > bd_e) { bd_e = nde; ce = 2 * p; }       // p ascending => lowest idx on tie
      if (ndo > bd_o) { bd_o = ndo; co = 2 * p + 1; }
    }

    // full u64 keys (dist_bits<<32 | ~idx): u64 max == (max dist, then min idx)
    unsigned long long ke =
        ((unsigned long long)__float_as_uint(bd_e) << 32) | (unsigned)(~(unsigned)(ce * 512 + tid));
    unsigned long long ko =
        ((unsigned long long)__float_as_uint(bd_o) << 32) | (unsigned)(~(unsigned)(co * 512 + tid));
    unsigned long long key = ko > ke ? ko : ke;

    key = dpp_max_step<0x111, 0xF>(key);   // row_shr:1
    key = dpp_max_step<0x112, 0xF>(key);   // row_shr:2
    key = dpp_max_step<0x114, 0xF>(key);   // row_shr:4
    key = dpp_max_step<0x118, 0xF>(key);   // row_shr:8
    key = dpp_max_step<0x142, 0xA>(key);   // row_bcast:15 -> rows 1,3
    key = dpp_max_step<0x143, 0xC>(key);   // row_bcast:31 -> rows 2,3
    if (lane == 63) slots[t & 1][wave] = key;           // wave max lives in lane 63
    __syncthreads();                                    // the ONLY barrier per iter

    unsigned long long k0 = slots[t & 1][0], k1 = slots[t & 1][1];
    unsigned long long k2 = slots[t & 1][2], k3 = slots[t & 1][3];
    unsigned long long k4 = slots[t & 1][4], k5 = slots[t & 1][5];
    unsigned long long k6 = slots[t & 1][6], k7 = slots[t & 1][7];
    k0 = k1 > k0 ? k1 : k0;
    k2 = k3 > k2 ? k3 : k2;
    k4 = k5 > k4 ? k5 : k4;
    k6 = k7 > k6 ? k7 : k6;
    k0 = k2 > k0 ? k2 : k0;
    k4 = k6 > k4 ? k6 : k4;
    k0 = k4 > k0 ? k4 : k0;
    int gi = (int)(~(unsigned)(k0 & 0xFFFFFFFFull));
    far = gi;
    cx = s_x[gi]; cy = s_y[gi]; cz = s_z[gi];           // broadcast ds_read
  }
  __syncthreads();

  // coalesced endgame writes
#pragma unroll
  for (int j = 0; j < 2; j++) {
    int t = j * 512 + tid;
    float4 h = hist[t];
    out[OUT_FPS + b * 1024 + t] = h.w;                  // fps_idx as float
    out[b * 3072 + t]           = h.x;                  // new_xyz [B,3,S]
    out[b * 3072 + 1024 + t]    = h.y;
    out[b * 3072 + 2048 + t]    = h.z;
    newxyz[(b * 1024 + t) * 3 + 0] = h.x;               // ws copy [B,S,3]
    newxyz[(b * 1024 + t) * 3 + 1] = h.y;
    newxyz[(b * 1024 + t) * 3 + 2] = h.z;
  }
}

// ---------------------------------------------------------------- KNN (top-16)
// 16 threads per centroid (512 pts each, strided). Sorted top-16 insertion per
// chunk (strict < => stable == ascending idx on ties), then a 16-way
// tournament merge on u64-packed (dist_bits<<32)|idx keys (lex == (d, idx)).
__global__ __launch_bounds__(256)
void knn_kernel(const float* __restrict__ xyz, const float* __restrict__ newxyz,
                int* __restrict__ knn)
{
#pragma clang fp contract(off)
  __shared__ unsigned long long s_k[16][16 * 17];   // [cent][chunk*17 + k], 34 KB
  const int tid   = threadIdx.x;
  const int cl    = tid >> 4;
  const int chunk = tid & 15;
  const int csel  = blockIdx.x * 16 + cl;
  const int b     = csel >> 10;                     // block-uniform (64 blocks/batch)
  const float* xb = xyz + (size_t)b * 3 * NPTS;
  const float cx = newxyz[csel * 3 + 0];
  const float cy = newxyz[csel * 3 + 1];
  const float cz = newxyz[csel * 3 + 2];

  float nd[16]; int ni[16];
#pragma unroll
  for (int k = 0; k < 16; k++) { nd[k] = 3.4e38f; ni[k] = 0x7FFFFFFF; }

  for (int jj = 0; jj < 512; jj++) {
    int j = jj * 16 + chunk;
    float dx = xb[j] - cx, dy = xb[NPTS + j] - cy, dz = xb[2 * NPTS + j] - cz;
    float d  = (dx * dx + dy * dy) + dz * dz;
    float cv = d; int iv = j;
#pragma unroll
    for (int k = 0; k < 16; k++) {       // branchless sorted insertion (strict <)
      bool sw = cv < nd[k];
      float tv = nd[k]; int ti = ni[k];
      nd[k] = sw ? cv : tv;  ni[k] = sw ? iv : ti;
      cv    = sw ? tv : cv;  iv    = sw ? ti : iv;
    }
  }
#pragma unroll
  for (int k = 0; k < 16; k++)
    s_k[cl][chunk * 17 + k] =
        ((unsigned long long)__float_as_uint(nd[k]) << 32) | (unsigned)ni[k];
  s_k[cl][chunk * 17 + 16] = ~0ull;      // sentinel
  __syncthreads();

  if (tid < 16) {                        // merge: 16 rounds of 16-way tournament (u64 min)
    int pos[16];
#pragma unroll
    for (int c = 0; c < 16; c++) pos[c] = 0;
    for (int r = 0; r < 16; r++) {
      unsigned long long bk = ~0ull; int bc = 0;
#pragma unroll
      for (int c = 0; c < 16; c++) {
        unsigned long long kv = s_k[tid][c * 17 + pos[c]];
        if (kv < bk) { bk = kv; bc = c; }
      }
#pragma unroll
      for (int c = 0; c < 16; c++) pos[c] += (c == bc);
      knn[(size_t)(blockIdx.x * 16 + tid) * 16 + r] = (int)(bk & 0xFFFFFFFFull);
    }
  }
}

// ---------------------------------------------------------------- gather + WeightNet + agg
// one wave per centroid (4 waves/block). agg[csel][c*16+w] = sum_k feat[k][c]*wts[k][w]
__global__ __launch_bounds__(256)
void feat_agg_kernel(const float* __restrict__ xyz, const float* __restrict__ newxyz,
                     const float* __restrict__ ptt, const int* __restrict__ knn,
                     const float* __restrict__ w1, const float* __restrict__ b1,
                     const float* __restrict__ w2, const float* __restrict__ b2,
                     const float* __restrict__ w3, const float* __restrict__ b3,
                     float* __restrict__ agg)
{
  const int wv   = threadIdx.x >> 6;
  const int lane = threadIdx.x & 63;
  const int csel = blockIdx.x * 4 + wv;
  const int b    = csel >> 10;

  __shared__ float s_wts[4][16 * 17];
  __shared__ float s_off[4][16 * 3];
  __shared__ int   s_nk[4][16];

  if (lane < 16) {
    int nk = knn[(size_t)csel * 16 + lane];
    s_nk[wv][lane] = nk;
    const float* xb = xyz + (size_t)b * 3 * NPTS;
    float ox = xb[nk]            - newxyz[csel * 3 + 0];
    float oy = xb[NPTS + nk]     - newxyz[csel * 3 + 1];
    float oz = xb[2 * NPTS + nk] - newxyz[csel * 3 + 2];
    s_off[wv][lane * 3 + 0] = ox;
    s_off[wv][lane * 3 + 1] = oy;
    s_off[wv][lane * 3 + 2] = oz;
    float h1[8], h2[8];
#pragma unroll
    for (int j = 0; j < 8; j++)
      h1[j] = fmaxf(0.f, ox * w1[j] + oy * w1[8 + j] + oz * w1[16 + j] + b1[j]);
#pragma unroll
    for (int j = 0; j < 8; j++) {
      float a = b2[j];
#pragma unroll
      for (int i = 0; i < 8; i++) a = fmaf(h1[i], w2[i * 8 + j], a);
      h2[j] = fmaxf(0.f, a);
    }
#pragma unroll
    for (int w = 0; w < 16; w++) {
      float a = b3[w];
#pragma unroll
      for (int i = 0; i < 8; i++) a = fmaf(h2[i], w3[i * 16 + w], a);
      s_wts[wv][lane * 17 + w] = fmaxf(0.f, a);
    }
  }
  __syncthreads();

  // gather point-feature channel d = lane for all 16 neighbors
  float f[16];
#pragma unroll
  for (int k = 0; k < 16; k++) {
    int nk = s_nk[wv][k];
    f[k] = ptt[((size_t)b * NPTS + nk) * D + lane];
  }

  float acc[16];
#pragma unroll
  for (int w = 0; w < 16; w++) acc[w] = 0.f;
#pragma unroll
  for (int k = 0; k < 16; k++) {
#pragma unroll
    for (int w = 0; w < 16; w++)
      acc[w] = fmaf(f[k], s_wts[wv][k * 17 + w], acc[w]);
  }
  float* arow = agg + (size_t)csel * (CIN * WN) + (3 + lane) * 16;
#pragma unroll
  for (int q = 0; q < 4; q++) {
    float4 v = make_float4(acc[4 * q], acc[4 * q + 1], acc[4 * q + 2], acc[4 * q + 3]);
    *(float4*)(arow + 4 * q) = v;
  }

  if (lane < 48) {                      // xyz-offset channels c = 0..2
    int c = lane >> 4, w = lane & 15;
    float a = 0.f;
#pragma unroll
    for (int k = 0; k < 16; k++)
      a = fmaf(s_off[wv][k * 3 + c], s_wts[wv][k * 17 + w], a);
    agg[(size_t)csel * (CIN * WN) + c * 16 + w] = a;
  }
}

// ---------------------------------------------------------------- GEMM [8192,1072]x[1072,128] + bias + leaky, transposed store
__global__ __launch_bounds__(256)
void gemm_out_kernel(const float* __restrict__ agg, const float* __restrict__ lin_w,
                     const float* __restrict__ lin_b, float* __restrict__ out)
{
  __shared__ float a_t[16 * 68];   // [k][r], stride 68
  __shared__ float b_t[16 * 64];   // [k][c]
  const int tid  = threadIdx.x;
  const int rt   = blockIdx.x >> 1;
  const int ct   = blockIdx.x & 1;
  const int row0 = rt * 64;
  const int c0   = ct * 64;
  const int cg   = tid & 31;   // 2 cols
  const int rg   = tid >> 5;   // 8 rows

  float acc[8][2] = {};
  for (int kt = 0; kt < 67; kt++) {
    const int k0 = kt * 16;
#pragma unroll
    for (int i = 0; i < 4; i++) {
      int s = tid + i * 256;
      int kk = s & 15, r = s >> 4;
      a_t[kk * 68 + r] = agg[(size_t)(row0 + r) * (CIN * WN) + k0 + kk];
    }
#pragma unroll
    for (int i = 0; i < 4; i++) {
      int s = tid + i * 256;
      int c = s & 63, kk = s >> 6;
      b_t[kk * 64 + c] = lin_w[(size_t)(k0 + kk) * OUTC + c0 + c];
    }
    __syncthreads();
#pragma unroll
    for (int kk = 0; kk < 16; kk++) {
      const float4 a0 = *(const float4*)&a_t[kk * 68 + rg * 8];
      const float4 a1 = *(const float4*)&a_t[kk * 68 + rg * 8 + 4];
      float bv0 = b_t[kk * 64 + cg * 2];
      float bv1 = b_t[kk * 64 + cg * 2 + 1];
      float av[8] = {a0.x, a0.y, a0.z, a0.w, a1.x, a1.y, a1.z, a1.w};
#pragma unroll
      for (int rr = 0; rr < 8; rr++) {
        acc[rr][0] = fmaf(av[rr], bv0, acc[rr][0]);
        acc[rr][1] = fmaf(av[rr], bv1, acc[rr][1]);
      }
    }
    __syncthreads();
  }
#pragma unroll
  for (int rr = 0; rr < 8; rr++) {
#pragma unroll
    for (int cc = 0; cc < 2; cc++) {
      int R = row0 + rg * 8 + rr;
      int C = c0 + cg * 2 + cc;
      float v = acc[rr][cc] + lin_b[C];
      v = v > 0.f ? v : 0.1f * v;
      int bb = R >> 10, ss = R & 1023;
      out[OUT_MAIN + ((size_t)(bb * OUTC + C)) * 1024 + ss] = v;
    }
  }
}

// ---------------------------------------------------------------- launch
extern "C" void kernel_launch(void* const* d_in, const int* in_sizes, int n_in,
                              void* d_out, int out_size, void* d_ws, size_t ws_size,
                              hipStream_t stream) {
  const float* xyz    = (const float*)d_in[0];
  const float* points = (const float*)d_in[1];
  const float* w1     = (const float*)d_in[2];
  const float* b1     = (const float*)d_in[3];
  const float* w2     = (const float*)d_in[4];
  const float* b2     = (const float*)d_in[5];
  const float* w3     = (const float*)d_in[6];
  const float* b3     = (const float*)d_in[7];
  const float* lin_w  = (const float*)d_in[8];
  const float* lin_b  = (const float*)d_in[9];
  float* out = (float*)d_out;
  char*  ws  = (char*)d_ws;

  float* newxyz = (float*)(ws);                 // [8,1024,3]      98304 B
  int*   knn    = (int*)  (ws + 98304);         // [8192,16]       524288 B
  float* ptt    = (float*)(ws + 1048576);       // [8,8192,64]     16 MiB
  float* agg    = (float*)(ws + 17825792);      // [8192,1072]     ~33.5 MiB

  stage0_kernel<<<8 + NBATCH * 128, 512, 0, stream>>>(xyz, points, newxyz, ptt, out);
  knn_kernel<<<512, 256, 0, stream>>>(xyz, newxyz, knn);
  feat_agg_kernel<<<2048, 256, 0, stream>>>(xyz, newxyz, ptt, knn,
                                            w1, b1, w2, b2, w3, b3, agg);
  gemm_out_kernel<<<256, 256, 0, stream>>>(agg, lin_w, lin_b, out);
}